// Round 2
// baseline (504.093 us; speedup 1.0000x reference)
//
#include <hip/hip_runtime.h>
#include <math.h>

#define NN 50000
#define NE 800000
#define EBLOCKS (NE / 64)          // 12500 edge blocks
#define WBLOCKS ((NN + 63) / 64)   // 782 world blocks

typedef float  f32x4  __attribute__((ext_vector_type(4)));
typedef __bf16 bf16x8 __attribute__((ext_vector_type(8)));
typedef short  s16x2  __attribute__((ext_vector_type(2)));

// ws layout: [0,256) m_agg_w (64 f32). [256,188672) bf16 weight fragments,
// 16B chunks, fragment-linear (chunk = tile*64 + lane). [188672,...) bf16
// m_agg_h accumulator [NN][64] (6.4 MB) when ws_size permits.
#define WE1F_OFF 0        // 5120: We1||Wg1  (kc<5, ct<16)  K 136->160
#define WE2F_OFF 5120     // 1024: We2       (kc<4, ct<4)
#define WN1F_OFF 6144     // 2048: Wn1       (kc<4, ct<8)
#define WN2F_OFF 8192     // 1024: Wn2       (kc<4, ct<4)
#define WW1F_OFF 9216     // 1536: Ww1       (kc<3, ct<8)   K 67->96
#define WW2F_OFF 10752    // 1024: Ww2       (kc<4, ct<4)
#define NCHUNKS  11776
#define MAGG_OFF (256 + NCHUNKS * 16)        // 188672, 256B-aligned
#define MAGG_BYTES ((size_t)NN * 64 * 2)     // 6.4 MB bf16

__device__ inline bf16x8 pack8(float4 a, float4 b) {
    bf16x8 r;
    r[0] = (__bf16)a.x; r[1] = (__bf16)a.y; r[2] = (__bf16)a.z; r[3] = (__bf16)a.w;
    r[4] = (__bf16)b.x; r[5] = (__bf16)b.y; r[6] = (__bf16)b.z; r[7] = (__bf16)b.w;
    return r;
}

__device__ inline float4 add4(float4 a, float4 b) {
    a.x += b.x; a.y += b.y; a.z += b.z; a.w += b.w; return a;
}

// packed 2x bf16 atomic fadd (CDNA3/4 global_atomic_pk_add_bf16).
// Halves atomic op count AND bytes vs 2x scalar f32 atomicAdd.
__device__ inline void pk_atomic_add_bf16(__bf16* addr, float a, float b) {
    union { s16x2 s; __bf16 h[2]; } u;
    u.h[0] = (__bf16)a; u.h[1] = (__bf16)b;
#if __has_builtin(__builtin_amdgcn_global_atomic_fadd_v2bf16)
    __builtin_amdgcn_global_atomic_fadd_v2bf16((s16x2*)addr, u.s);
#else
    asm volatile("global_atomic_pk_add_bf16 %0, %1, off"
                 :: "v"(addr), "v"(u.s) : "memory");
#endif
}

// ---------------- weight fragment pre-pack ----------------
__global__ __launch_bounds__(256) void pack_weights(
    const float* __restrict__ We1, const float* __restrict__ Wg1,
    const float* __restrict__ We2, const float* __restrict__ Wn1,
    const float* __restrict__ Wn2, const float* __restrict__ Ww1,
    const float* __restrict__ Ww2, bf16x8* __restrict__ wsF)
{
    int c = blockIdx.x * 256 + threadIdx.x;
    if (c >= NCHUNKS) return;
    const int lane = c & 63, l16 = lane & 15, row8 = ((lane >> 4) & 3) * 8;
    bf16x8 p;
    if (c < WE2F_OFF) {                       // We1 || Wg1, pad K 136->160
        int ct = (c >> 6) & 15, kc = c >> 10;
        int col = ct * 16 + l16;
        const float* src = (col < 128) ? (We1 + col) : (Wg1 + (col - 128));
#pragma unroll
        for (int i = 0; i < 8; i++) {
            int r = kc * 32 + row8 + i;
            p[i] = (__bf16)((r < 136) ? src[(size_t)r * 128] : 0.f);
        }
    } else if (c < WN1F_OFF) {
        int cc = c - WE2F_OFF; int ct = (cc >> 6) & 3, kc = cc >> 8;
        int col = ct * 16 + l16;
#pragma unroll
        for (int i = 0; i < 8; i++)
            p[i] = (__bf16)We2[(size_t)(kc * 32 + row8 + i) * 64 + col];
    } else if (c < WN2F_OFF) {
        int cc = c - WN1F_OFF; int ct = (cc >> 6) & 7, kc = cc >> 9;
        int col = ct * 16 + l16;
#pragma unroll
        for (int i = 0; i < 8; i++)
            p[i] = (__bf16)Wn1[(size_t)(kc * 32 + row8 + i) * 128 + col];
    } else if (c < WW1F_OFF) {
        int cc = c - WN2F_OFF; int ct = (cc >> 6) & 3, kc = cc >> 8;
        int col = ct * 16 + l16;
#pragma unroll
        for (int i = 0; i < 8; i++)
            p[i] = (__bf16)Wn2[(size_t)(kc * 32 + row8 + i) * 64 + col];
    } else if (c < WW2F_OFF) {                // Ww1, pad K 67->96
        int cc = c - WW1F_OFF; int ct = (cc >> 6) & 7, kc = cc >> 9;
        int col = ct * 16 + l16;
#pragma unroll
        for (int i = 0; i < 8; i++) {
            int r = kc * 32 + row8 + i;
            p[i] = (__bf16)((r < 67) ? Ww1[(size_t)r * 128 + col] : 0.f);
        }
    } else {
        int cc = c - WW2F_OFF; int ct = (cc >> 6) & 3, kc = cc >> 8;
        int col = ct * 16 + l16;
#pragma unroll
        for (int i = 0; i < 8; i++)
            p[i] = (__bf16)Ww2[(size_t)(kc * 32 + row8 + i) * 64 + col];
    }
    wsF[c] = p;
}

// --------- fused edge + world kernel: blocks [0,EBLOCKS) = edges, rest = world
// Edge path: R6 structure — 64 edges/block, 8 waves, wave owns 2 GEMM1
// col-tiles (waves 0-3 message, 4-7 gate), weights read once/block with
// register double-buffer prefetch. GEMM2 is computed TRANSPOSED
// (D = We2^T @ H^T; A/B frag layouts are symmetric so We2F/HF reuse as-is):
// each thread then owns 4 consecutive message columns of one edge ->
// packed v2bf16 atomics (2 ops per thread per edge-tile).
// World path: R7 structure.
union FusedLds {
    bf16x8 XF[1280];     // edge XF 20 KB (world uses first 768)
    bf16x8 HF[1024];     // HF 16 KB (both paths)
};

__global__ __launch_bounds__(512, 6) void fused_kernel(
    const float* __restrict__ z_h, const int* __restrict__ ei,
    const bf16x8* __restrict__ We1F, const bf16x8* __restrict__ We2F,
    const float* __restrict__ be1, const float* __restrict__ be2,
    const float* __restrict__ bg1, const float* __restrict__ Wg2,
    const float* __restrict__ bg2,
    const float* __restrict__ pos_world,
    const bf16x8* __restrict__ Ww1F, const bf16x8* __restrict__ Ww2F,
    const float* __restrict__ bw1, const float* __restrict__ bw2,
    float* __restrict__ m_agg_h, __bf16* __restrict__ m_agg_b,
    float* __restrict__ m_agg_w, int bmode)
{
    __shared__ FusedLds U;
    __shared__ int   tgt_s[64];
    __shared__ float gred[4][64];
    __shared__ float wgt[64];

    const int t = threadIdx.x;               // 0..511
    const int lane = t & 63, w = t >> 6;     // w 0..7
    const int quad = lane >> 4, l16 = lane & 15;

    if (blockIdx.x >= EBLOCKS) {
        // ================= world path (R7) =================
        const int n0 = (blockIdx.x - EBLOCKS) * 64;
        {   // gather
            int nn = t >> 3, q = t & 7;
            int mt = nn >> 4, l16e = nn & 15;
            int node = n0 + nn; if (node >= NN) node = NN - 1;
            if (q < 4) {
                const float4* zr = (const float4*)(z_h + (long)node * 64) + q * 4;
                float4 a0 = zr[0], a1 = zr[1], a2 = zr[2], a3 = zr[3];
                int kcs = q >> 1, qa = (q & 1) * 2;
                U.XF[(kcs * 4 + mt) * 64 + qa * 16 + l16e]       = pack8(a0, a1);
                U.XF[(kcs * 4 + mt) * 64 + (qa + 1) * 16 + l16e] = pack8(a2, a3);
            } else if (q == 4) {
                float4 a0 = *(const float4*)(z_h + (long)node * 64);
                bf16x8 f;
#pragma unroll
                for (int i = 0; i < 8; i++) f[i] = (__bf16)0.f;
                f[0] = (__bf16)(a0.x - pos_world[0]);
                f[1] = (__bf16)(a0.y - pos_world[1]);
                f[2] = (__bf16)(a0.z - pos_world[2]);
                U.XF[(8 + mt) * 64 + l16e] = f;
            } else {
                bf16x8 z;
#pragma unroll
                for (int i = 0; i < 8; i++) z[i] = (__bf16)0.f;
                U.XF[(8 + mt) * 64 + (q - 4) * 16 + l16e] = z;
            }
        }
        __syncthreads();

        f32x4 acc[4];
        {
            float b = bw1[w * 16 + l16];
#pragma unroll
            for (int mt = 0; mt < 4; mt++) { f32x4 v = {b, b, b, b}; acc[mt] = v; }
        }
#pragma unroll
        for (int kc = 0; kc < 3; kc++) {
            bf16x8 bfr = Ww1F[(kc * 8 + w) * 64 + lane];
#pragma unroll
            for (int mt = 0; mt < 4; mt++)
                acc[mt] = __builtin_amdgcn_mfma_f32_16x16x32_bf16(
                    U.XF[(kc * 4 + mt) * 64 + lane], bfr, acc[mt], 0, 0, 0);
        }
        __syncthreads();

        {   // relu + transpose -> HF
            __bf16* HFp = (__bf16*)U.HF;
            int cw = w * 16 + l16;
            int kc2 = cw >> 5, quad2 = (cw >> 3) & 3, ii = cw & 7;
#pragma unroll
            for (int mt = 0; mt < 4; mt++)
#pragma unroll
                for (int r = 0; r < 4; r++)
                    HFp[(((kc2 * 4 + mt) * 64) + quad2 * 16 + quad * 4 + r) * 8 + ii] =
                        (__bf16)fmaxf(acc[mt][r], 0.f);
        }
        __syncthreads();

        {   // GEMM2 + masked column-sum
            const int nt = w & 3, mh = w >> 2;
            f32x4 acc2[2];
            float b2 = bw2[nt * 16 + l16];
#pragma unroll
            for (int m = 0; m < 2; m++) { f32x4 v = {b2, b2, b2, b2}; acc2[m] = v; }
#pragma unroll
            for (int kc = 0; kc < 4; kc++) {
                bf16x8 b2f = Ww2F[(kc * 4 + nt) * 64 + lane];
#pragma unroll
                for (int m = 0; m < 2; m++)
                    acc2[m] = __builtin_amdgcn_mfma_f32_16x16x32_bf16(
                        U.HF[(kc * 4 + mh * 2 + m) * 64 + lane], b2f, acc2[m], 0, 0, 0);
            }
            float s = 0.f;
#pragma unroll
            for (int m = 0; m < 2; m++)
#pragma unroll
                for (int r = 0; r < 4; r++) {
                    int node = n0 + (mh * 2 + m) * 16 + quad * 4 + r;
                    s += (node < NN) ? acc2[m][r] : 0.f;
                }
            s += __shfl_xor(s, 16, 64);
            s += __shfl_xor(s, 32, 64);
            if (quad == 0) atomicAdd(m_agg_w + nt * 16 + l16, s);
        }
        return;
    }

    // ================= edge path (R6 + B-frag register dbuf) =================
    const int e0 = blockIdx.x * 64;          // NE % 64 == 0

    {   // ---- gather: 8 threads/edge (side 0 = src, side 1 = tgt) ----
        const int ee = t >> 3, q = t & 7;
        const int side = q >> 2, sub = q & 3;
        const int mt = ee >> 4, l16e = ee & 15;
        const int eg = e0 + ee;
        const int row = side ? ei[NE + eg] : ei[eg];
        if (q == 4) tgt_s[ee] = row;
        const float4* zr = (const float4*)(z_h + (long)row * 64) + sub * 4;
        float4 a0 = zr[0], a1 = zr[1], a2 = zr[2], a3 = zr[3];
        const int kcs = (sub >> 1) + side * 2, qa = (sub & 1) * 2;
        U.XF[(kcs * 4 + mt) * 64 + qa * 16 + l16e]       = pack8(a0, a1);
        U.XF[(kcs * 4 + mt) * 64 + (qa + 1) * 16 + l16e] = pack8(a2, a3);
        if (q == 0) {       // edge features (cols 128..135)
            const float4* zt = (const float4*)(z_h + (long)ei[NE + eg] * 64);
            float4 t0 = zt[0], t1 = zt[1];
            float dx = a0.x - t0.x, dy = a0.y - t0.y, dz = a0.z - t0.z;
            float ax = a0.w, ay = a1.x, az = a1.y;
            float bx = t0.w, by = t1.x, bz = t1.y;
            float cx = ay * bz - az * by;
            float cy = az * bx - ax * bz;
            float cz = ax * by - ay * bx;
            bf16x8 f;
            f[0] = (__bf16)dx; f[1] = (__bf16)dy; f[2] = (__bf16)dz;
            f[3] = (__bf16)(dx * dx + dy * dy + dz * dz);
            f[4] = (__bf16)cx; f[5] = (__bf16)cy; f[6] = (__bf16)cz;
            f[7] = (__bf16)sqrtf(cx * cx + cy * cy + cz * cz);
            U.XF[(16 + mt) * 64 + l16e] = f;
        } else if (q >= 5) { // zero pad (cols 136..159)
            bf16x8 z;
#pragma unroll
            for (int i = 0; i < 8; i++) z[i] = (__bf16)0.f;
            U.XF[(16 + mt) * 64 + (q - 4) * 16 + l16e] = z;
        }
    }
    __syncthreads();                         // B1: XF ready

    // ---- GEMM1: wave owns 32 cols (tiles 2w, 2w+1), 1-ahead B prefetch ----
    f32x4 acc[4][2];
#pragma unroll
    for (int nt = 0; nt < 2; nt++) {
        int col = (w * 2 + nt) * 16 + l16;
        float b = (col < 128) ? be1[col] : bg1[col - 128];
#pragma unroll
        for (int mt = 0; mt < 4; mt++) { f32x4 v = {b, b, b, b}; acc[mt][nt] = v; }
    }
    bf16x8 bcur0 = We1F[(w * 2) * 64 + lane];
    bf16x8 bcur1 = We1F[(w * 2 + 1) * 64 + lane];
#pragma unroll
    for (int kc = 0; kc < 5; kc++) {
        bf16x8 bnx0, bnx1;
        if (kc < 4) {
            bnx0 = We1F[((kc + 1) * 16 + w * 2) * 64 + lane];
            bnx1 = We1F[((kc + 1) * 16 + w * 2 + 1) * 64 + lane];
        }
#pragma unroll
        for (int mt = 0; mt < 4; mt++) {
            bf16x8 af = U.XF[(kc * 4 + mt) * 64 + lane];
            acc[mt][0] = __builtin_amdgcn_mfma_f32_16x16x32_bf16(af, bcur0, acc[mt][0], 0, 0, 0);
            acc[mt][1] = __builtin_amdgcn_mfma_f32_16x16x32_bf16(af, bcur1, acc[mt][1], 0, 0, 0);
        }
        bcur0 = bnx0; bcur1 = bnx1;
    }
    __syncthreads();                         // B2: XF reads done (HF may overwrite)

    if (w < 4) {
        // ---- message waves: relu + transpose into HF (GEMM2-A order) ----
        __bf16* HFp = (__bf16*)U.HF;
#pragma unroll
        for (int nt = 0; nt < 2; nt++) {
            int cw = (w * 2 + nt) * 16 + l16;
            int kc2 = cw >> 5, quad2 = (cw >> 3) & 3, ii = cw & 7;
#pragma unroll
            for (int mt = 0; mt < 4; mt++)
#pragma unroll
                for (int r = 0; r < 4; r++)
                    HFp[(((kc2 * 4 + mt) * 64) + quad2 * 16 + quad * 4 + r) * 8 + ii] =
                        (__bf16)fmaxf(acc[mt][nt][r], 0.f);
        }
    } else {
        // ---- gate waves: in-register partials over their 32 gate cols ----
        float gp[4][4];
#pragma unroll
        for (int mt = 0; mt < 4; mt++)
#pragma unroll
            for (int r = 0; r < 4; r++) gp[mt][r] = 0.f;
#pragma unroll
        for (int nt = 0; nt < 2; nt++) {
            float wg = Wg2[((w - 4) * 2 + nt) * 16 + l16];
#pragma unroll
            for (int mt = 0; mt < 4; mt++)
#pragma unroll
                for (int r = 0; r < 4; r++)
                    gp[mt][r] += fmaxf(acc[mt][nt][r], 0.f) * wg;
        }
#pragma unroll
        for (int mask = 1; mask < 16; mask <<= 1)
#pragma unroll
            for (int mt = 0; mt < 4; mt++)
#pragma unroll
                for (int r = 0; r < 4; r++)
                    gp[mt][r] += __shfl_xor(gp[mt][r], mask, 64);
        if (l16 == 0) {
#pragma unroll
            for (int mt = 0; mt < 4; mt++)
#pragma unroll
                for (int r = 0; r < 4; r++)
                    gred[(w - 4) & 3][mt * 16 + quad * 4 + r] = gp[mt][r];
        }
    }
    __syncthreads();                         // B3: HF + gred ready

    if (t < 64) {                            // 64 sigmoids per block
        float g = bg2[0] + gred[0][t] + gred[1][t] + gred[2][t] + gred[3][t];
        wgt[t] = 1.f / (1.f + __expf(-g));
    }

    // ---- GEMM2 TRANSPOSED (all 8 waves): D[mc][edge] = We2^T @ H^T ----
    // A-frag = We2F (unchanged packing: lane&15 = msg col, quad = k-sub),
    // B-frag = HF (unchanged layout: lane&15 = edge, quad = k-sub).
    // wave w: mc-tile (w&3), edge tiles (w>>2)*2 .. +1.
    // D: row = quad*4+r = 4 consecutive msg cols; col = l16 = edge-in-tile.
    {
        const int mct = w & 3, etb = (w >> 2) * 2;
        const int mc0 = mct * 16 + quad * 4;
        f32x4 acc2[2];
        float4 b4 = *(const float4*)(be2 + mc0);
#pragma unroll
        for (int m = 0; m < 2; m++) {
            f32x4 v; v[0] = b4.x; v[1] = b4.y; v[2] = b4.z; v[3] = b4.w;
            acc2[m] = v;
        }
        bf16x8 a2 = We2F[mct * 64 + lane];
#pragma unroll
        for (int kc = 0; kc < 4; kc++) {
            bf16x8 n2;
            if (kc < 3) n2 = We2F[((kc + 1) * 4 + mct) * 64 + lane];
#pragma unroll
            for (int m = 0; m < 2; m++)
                acc2[m] = __builtin_amdgcn_mfma_f32_16x16x32_bf16(
                    a2, U.HF[(kc * 4 + etb + m) * 64 + lane], acc2[m], 0, 0, 0);
            a2 = n2;
        }
        __syncthreads();                     // B4: wgt ready

        // ---- scatter: w * m -> target rows ----
        if (bmode) {
#pragma unroll
            for (int m = 0; m < 2; m++) {
                int edge = (etb + m) * 16 + l16;
                float wg = wgt[edge];
                __bf16* p = m_agg_b + (long)tgt_s[edge] * 64 + mc0;
                pk_atomic_add_bf16(p,     acc2[m][0] * wg, acc2[m][1] * wg);
                pk_atomic_add_bf16(p + 2, acc2[m][2] * wg, acc2[m][3] * wg);
            }
        } else {
#pragma unroll
            for (int m = 0; m < 2; m++) {
                int edge = (etb + m) * 16 + l16;
                float wg = wgt[edge];
                float* p = m_agg_h + (long)tgt_s[edge] * 64 + mc0;
#pragma unroll
                for (int r = 0; r < 4; r++)
                    atomicAdd(p + r, acc2[m][r] * wg);
            }
        }
    }
}

// ---------------- node kernel: 512 thr, N-split, weights once/block ---------
__global__ __launch_bounds__(512, 4) void node_kernel(
    const float* __restrict__ z_h,
    const float* __restrict__ m_agg_h, const __bf16* __restrict__ m_agg_b,
    const float* __restrict__ m_agg_w,
    const bf16x8* __restrict__ Wn1F, const bf16x8* __restrict__ Wn2F,
    const float* __restrict__ bn1, const float* __restrict__ bn2,
    float* __restrict__ outp, int bmode)
{
    __shared__ union { bf16x8 XF[1024]; bf16x8 HF[1024]; } U;   // 16 KB
    const int t = threadIdx.x;
    const int n0 = blockIdx.x * 64;
    const int lane = t & 63, w = t >> 6;
    const int quad = lane >> 4, l16 = lane & 15;

    {   // gather: 8 threads/node; halves: z | m_agg(+m_agg_w)
        int nn = t >> 3, q = t & 7;
        int mt = nn >> 4, l16e = nn & 15;
        int node = n0 + nn; if (node >= NN) node = NN - 1;
        int half = q >> 2, sub = q & 3;
        bf16x8 c0, c1;
        if (half == 0) {
            const float4* zr = (const float4*)(z_h + (long)node * 64) + sub * 4;
            c0 = pack8(zr[0], zr[1]);
            c1 = pack8(zr[2], zr[3]);
        } else if (bmode) {
            const bf16x8* mr = (const bf16x8*)(m_agg_b + (long)node * 64) + sub * 2;
            bf16x8 r0 = mr[0], r1 = mr[1];
            const float* mw = m_agg_w + sub * 16;
#pragma unroll
            for (int i = 0; i < 8; i++) {
                c0[i] = (__bf16)((float)r0[i] + mw[i]);
                c1[i] = (__bf16)((float)r1[i] + mw[i + 8]);
            }
        } else {
            const float4* mr = (const float4*)(m_agg_h + (long)node * 64) + sub * 4;
            const float4* mw = (const float4*)m_agg_w + sub * 4;
            c0 = pack8(add4(mr[0], mw[0]), add4(mr[1], mw[1]));
            c1 = pack8(add4(mr[2], mw[2]), add4(mr[3], mw[3]));
        }
        int kcs = (sub >> 1) + half * 2, qa = (sub & 1) * 2;
        U.XF[(kcs * 4 + mt) * 64 + qa * 16 + l16e]       = c0;
        U.XF[(kcs * 4 + mt) * 64 + (qa + 1) * 16 + l16e] = c1;
    }
    __syncthreads();                         // B1

    f32x4 acc[4];
    {
        float b = bn1[w * 16 + l16];
#pragma unroll
        for (int mt = 0; mt < 4; mt++) { f32x4 v = {b, b, b, b}; acc[mt] = v; }
    }
#pragma unroll
    for (int kc = 0; kc < 4; kc++) {
        bf16x8 bfr = Wn1F[(kc * 8 + w) * 64 + lane];
#pragma unroll
        for (int mt = 0; mt < 4; mt++)
            acc[mt] = __builtin_amdgcn_mfma_f32_16x16x32_bf16(
                U.XF[(kc * 4 + mt) * 64 + lane], bfr, acc[mt], 0, 0, 0);
    }
    __syncthreads();                         // B2

    {   // relu + transpose -> HF
        __bf16* HFp = (__bf16*)U.HF;
        int cw = w * 16 + l16;
        int kc2 = cw >> 5, quad2 = (cw >> 3) & 3, ii = cw & 7;
#pragma unroll
        for (int mt = 0; mt < 4; mt++)
#pragma unroll
            for (int r = 0; r < 4; r++)
                HFp[(((kc2 * 4 + mt) * 64) + quad2 * 16 + quad * 4 + r) * 8 + ii] =
                    (__bf16)fmaxf(acc[mt][r], 0.f);
    }
    __syncthreads();                         // B3

    {   // GEMM2 + store: nt = w&3, m-half mh = w>>2
        const int nt = w & 3, mh = w >> 2;
        f32x4 acc2[2];
        float b2 = bn2[nt * 16 + l16];
#pragma unroll
        for (int m = 0; m < 2; m++) { f32x4 v = {b2, b2, b2, b2}; acc2[m] = v; }
#pragma unroll
        for (int kc = 0; kc < 4; kc++) {
            bf16x8 b2f = Wn2F[(kc * 4 + nt) * 64 + lane];
#pragma unroll
            for (int m = 0; m < 2; m++)
                acc2[m] = __builtin_amdgcn_mfma_f32_16x16x32_bf16(
                    U.HF[(kc * 4 + mh * 2 + m) * 64 + lane], b2f, acc2[m], 0, 0, 0);
        }
#pragma unroll
        for (int m = 0; m < 2; m++)
#pragma unroll
            for (int r = 0; r < 4; r++) {
                int node = n0 + (mh * 2 + m) * 16 + quad * 4 + r;
                if (node < NN)
                    outp[(long)node * 64 + nt * 16 + l16] = acc2[m][r];
            }
    }
}

extern "C" void kernel_launch(void* const* d_in, const int* in_sizes, int n_in,
                              void* d_out, int out_size, void* d_ws, size_t ws_size,
                              hipStream_t stream)
{
    const float* z_h       = (const float*)d_in[0];
    const float* pos_world = (const float*)d_in[1];
    const int*   ei        = (const int*)d_in[2];
    const float* We1 = (const float*)d_in[3];  const float* be1 = (const float*)d_in[4];
    const float* We2 = (const float*)d_in[5];  const float* be2 = (const float*)d_in[6];
    const float* Wg1 = (const float*)d_in[7];  const float* bg1 = (const float*)d_in[8];
    const float* Wg2 = (const float*)d_in[9];  const float* bg2 = (const float*)d_in[10];
    const float* Wn1 = (const float*)d_in[11]; const float* bn1 = (const float*)d_in[12];
    const float* Wn2 = (const float*)d_in[13]; const float* bn2 = (const float*)d_in[14];
    const float* Ww1 = (const float*)d_in[15]; const float* bw1 = (const float*)d_in[16];
    const float* Ww2 = (const float*)d_in[17]; const float* bw2 = (const float*)d_in[18];

    float*  outp    = (float*)d_out;
    float*  m_agg_h = outp;                 // fallback: d_out doubles as f32 accumulator
    float*  m_agg_w = (float*)d_ws;         // 64 floats
    bf16x8* wsF     = (bf16x8*)((char*)d_ws + 256);
    __bf16* m_agg_b = (__bf16*)((char*)d_ws + MAGG_OFF);

    const int bmode = (ws_size >= (size_t)MAGG_OFF + MAGG_BYTES) ? 1 : 0;

    if (bmode) {
        hipMemsetAsync(d_ws, 0, 256, stream);
        hipMemsetAsync((char*)d_ws + MAGG_OFF, 0, MAGG_BYTES, stream);
    } else {
        hipMemsetAsync(d_out, 0, (size_t)NN * 64 * sizeof(float), stream);
        hipMemsetAsync(d_ws, 0, 256, stream);
    }

    pack_weights<<<(NCHUNKS + 255) / 256, 256, 0, stream>>>(
        We1, Wg1, We2, Wn1, Wn2, Ww1, Ww2, wsF);
    fused_kernel<<<EBLOCKS + WBLOCKS, 512, 0, stream>>>(
        z_h, ei, wsF + WE1F_OFF, wsF + WE2F_OFF,
        be1, be2, bg1, Wg2, bg2,
        pos_world, wsF + WW1F_OFF, wsF + WW2F_OFF, bw1, bw2,
        m_agg_h, m_agg_b, m_agg_w, bmode);
    node_kernel<<<(NN + 63) / 64, 512, 0, stream>>>(
        z_h, m_agg_h, m_agg_b, m_agg_w, wsF + WN1F_OFF, wsF + WN2F_OFF,
        bn1, bn2, outp, bmode);
}

// Round 3
// 295.739 us; speedup vs baseline: 1.7045x; 1.7045x over previous
//
#include <hip/hip_runtime.h>
#include <math.h>

#define NN 50000
#define NE 800000
#define EBLOCKS (NE / 64)          // 12500 edge blocks
#define WBLOCKS ((NN + 63) / 64)   // 782 world blocks

typedef float     f32x4  __attribute__((ext_vector_type(4)));
typedef __bf16    bf16x8 __attribute__((ext_vector_type(8)));
typedef _Float16  f16x2  __attribute__((ext_vector_type(2)));
typedef _Float16  f16x8  __attribute__((ext_vector_type(8)));

// ws layout: [0,256) m_agg_w (64 f32). [256,...) bf16 weight fragments,
// 16B chunks, fragment-linear (chunk = tile*64 + lane):
#define WE1F_OFF 0        // 5120: We1||Wg1  (kc<5, ct<16)  K 136->160
#define WE2F_OFF 5120     // 1024: We2       (kc<4, ct<4)
#define WN1F_OFF 6144     // 2048: Wn1       (kc<4, ct<8)
#define WN2F_OFF 8192     // 1024: Wn2       (kc<4, ct<4)
#define WW1F_OFF 9216     // 1536: Ww1       (kc<3, ct<8)   K 67->96
#define WW2F_OFF 10752    // 1024: Ww2       (kc<4, ct<4)
#define NCHUNKS  11776

// m_agg_h accumulator: f16[64] packed in the FIRST 128 B of each 256 B
// output row (d_out row n = bytes [n*256, n*256+256)). node_kernel block n
// is the only reader of acc row n and only writer of out row n, read
// before write -> no cross-block race, zero extra storage.

__device__ inline bf16x8 pack8(float4 a, float4 b) {
    bf16x8 r;
    r[0] = (__bf16)a.x; r[1] = (__bf16)a.y; r[2] = (__bf16)a.z; r[3] = (__bf16)a.w;
    r[4] = (__bf16)b.x; r[5] = (__bf16)b.y; r[6] = (__bf16)b.z; r[7] = (__bf16)b.w;
    return r;
}

// packed 2x f16 atomic fadd (global_atomic_pk_add_f16, gfx90a+).
// Halves atomic op count AND bytes vs 2x scalar f32 atomicAdd.
__device__ inline void pk_atomic_add_f16(void* addr, f16x2 v) {
#if __has_builtin(__builtin_amdgcn_global_atomic_fadd_v2f16)
    __builtin_amdgcn_global_atomic_fadd_v2f16((f16x2*)addr, v);
#else
    asm volatile("global_atomic_pk_add_f16 %0, %1, off"
                 :: "v"(addr), "v"(v) : "memory");
#endif
}

// ---------------- weight fragment pre-pack ----------------
__global__ __launch_bounds__(256) void pack_weights(
    const float* __restrict__ We1, const float* __restrict__ Wg1,
    const float* __restrict__ We2, const float* __restrict__ Wn1,
    const float* __restrict__ Wn2, const float* __restrict__ Ww1,
    const float* __restrict__ Ww2, bf16x8* __restrict__ wsF)
{
    int c = blockIdx.x * 256 + threadIdx.x;
    if (c >= NCHUNKS) return;
    const int lane = c & 63, l16 = lane & 15, row8 = ((lane >> 4) & 3) * 8;
    bf16x8 p;
    if (c < WE2F_OFF) {                       // We1 || Wg1, pad K 136->160
        int ct = (c >> 6) & 15, kc = c >> 10;
        int col = ct * 16 + l16;
        const float* src = (col < 128) ? (We1 + col) : (Wg1 + (col - 128));
#pragma unroll
        for (int i = 0; i < 8; i++) {
            int r = kc * 32 + row8 + i;
            p[i] = (__bf16)((r < 136) ? src[(size_t)r * 128] : 0.f);
        }
    } else if (c < WN1F_OFF) {
        int cc = c - WE2F_OFF; int ct = (cc >> 6) & 3, kc = cc >> 8;
        int col = ct * 16 + l16;
#pragma unroll
        for (int i = 0; i < 8; i++)
            p[i] = (__bf16)We2[(size_t)(kc * 32 + row8 + i) * 64 + col];
    } else if (c < WN2F_OFF) {
        int cc = c - WN1F_OFF; int ct = (cc >> 6) & 7, kc = cc >> 9;
        int col = ct * 16 + l16;
#pragma unroll
        for (int i = 0; i < 8; i++)
            p[i] = (__bf16)Wn1[(size_t)(kc * 32 + row8 + i) * 128 + col];
    } else if (c < WW1F_OFF) {
        int cc = c - WN2F_OFF; int ct = (cc >> 6) & 3, kc = cc >> 8;
        int col = ct * 16 + l16;
#pragma unroll
        for (int i = 0; i < 8; i++)
            p[i] = (__bf16)Wn2[(size_t)(kc * 32 + row8 + i) * 64 + col];
    } else if (c < WW2F_OFF) {                // Ww1, pad K 67->96
        int cc = c - WW1F_OFF; int ct = (cc >> 6) & 7, kc = cc >> 9;
        int col = ct * 16 + l16;
#pragma unroll
        for (int i = 0; i < 8; i++) {
            int r = kc * 32 + row8 + i;
            p[i] = (__bf16)((r < 67) ? Ww1[(size_t)r * 128 + col] : 0.f);
        }
    } else {
        int cc = c - WW2F_OFF; int ct = (cc >> 6) & 3, kc = cc >> 8;
        int col = ct * 16 + l16;
#pragma unroll
        for (int i = 0; i < 8; i++)
            p[i] = (__bf16)Ww2[(size_t)(kc * 32 + row8 + i) * 64 + col];
    }
    wsF[c] = p;
}

// --------- fused edge + world kernel: blocks [0,EBLOCKS) = edges, rest = world
// Edge path = R0 structure (GEMM2: wave w<4 owns col-tile w, thread owns 1
// col x 16 edges) + NEW: weighted messages repack through padded LDS to f16,
// then all 8 waves scatter with packed v2f16 atomics (2048 ops/block vs 4096
// f32; per wave-instr: 2 target rows x 128 B = 4 cachelines x 16 lanes).
union FusedLds {
    bf16x8 XF[1280];                                   // edge XF 20 KB
    struct {
        bf16x8   HF[1024];                             // 16 KB (offset 0)
        _Float16 M[64 * 68];                           // 8.7 KB, stride 68 halfs
    } s;
};

__global__ __launch_bounds__(512, 6) void fused_kernel(
    const float* __restrict__ z_h, const int* __restrict__ ei,
    const bf16x8* __restrict__ We1F, const bf16x8* __restrict__ We2F,
    const float* __restrict__ be1, const float* __restrict__ be2,
    const float* __restrict__ bg1, const float* __restrict__ Wg2,
    const float* __restrict__ bg2,
    const float* __restrict__ pos_world,
    const bf16x8* __restrict__ Ww1F, const bf16x8* __restrict__ Ww2F,
    const float* __restrict__ bw1, const float* __restrict__ bw2,
    float* __restrict__ magg_rows,     // = d_out base; row n acc at n*256 B
    float* __restrict__ m_agg_w)
{
    __shared__ FusedLds U;
    __shared__ int   tgt_s[64];
    __shared__ float gred[4][64];
    __shared__ float wgt[64];

    const int t = threadIdx.x;               // 0..511
    const int lane = t & 63, w = t >> 6;     // w 0..7
    const int quad = lane >> 4, l16 = lane & 15;

    if (blockIdx.x >= EBLOCKS) {
        // ================= world path (R7) =================
        const int n0 = (blockIdx.x - EBLOCKS) * 64;
        {   // gather
            int nn = t >> 3, q = t & 7;
            int mt = nn >> 4, l16e = nn & 15;
            int node = n0 + nn; if (node >= NN) node = NN - 1;
            if (q < 4) {
                const float4* zr = (const float4*)(z_h + (long)node * 64) + q * 4;
                float4 a0 = zr[0], a1 = zr[1], a2 = zr[2], a3 = zr[3];
                int kcs = q >> 1, qa = (q & 1) * 2;
                U.XF[(kcs * 4 + mt) * 64 + qa * 16 + l16e]       = pack8(a0, a1);
                U.XF[(kcs * 4 + mt) * 64 + (qa + 1) * 16 + l16e] = pack8(a2, a3);
            } else if (q == 4) {
                float4 a0 = *(const float4*)(z_h + (long)node * 64);
                bf16x8 f;
#pragma unroll
                for (int i = 0; i < 8; i++) f[i] = (__bf16)0.f;
                f[0] = (__bf16)(a0.x - pos_world[0]);
                f[1] = (__bf16)(a0.y - pos_world[1]);
                f[2] = (__bf16)(a0.z - pos_world[2]);
                U.XF[(8 + mt) * 64 + l16e] = f;
            } else {
                bf16x8 z;
#pragma unroll
                for (int i = 0; i < 8; i++) z[i] = (__bf16)0.f;
                U.XF[(8 + mt) * 64 + (q - 4) * 16 + l16e] = z;
            }
        }
        __syncthreads();

        f32x4 acc[4];
        {
            float b = bw1[w * 16 + l16];
#pragma unroll
            for (int mt = 0; mt < 4; mt++) { f32x4 v = {b, b, b, b}; acc[mt] = v; }
        }
#pragma unroll
        for (int kc = 0; kc < 3; kc++) {
            bf16x8 bfr = Ww1F[(kc * 8 + w) * 64 + lane];
#pragma unroll
            for (int mt = 0; mt < 4; mt++)
                acc[mt] = __builtin_amdgcn_mfma_f32_16x16x32_bf16(
                    U.XF[(kc * 4 + mt) * 64 + lane], bfr, acc[mt], 0, 0, 0);
        }
        __syncthreads();

        {   // relu + transpose -> HF
            __bf16* HFp = (__bf16*)U.s.HF;
            int cw = w * 16 + l16;
            int kc2 = cw >> 5, quad2 = (cw >> 3) & 3, ii = cw & 7;
#pragma unroll
            for (int mt = 0; mt < 4; mt++)
#pragma unroll
                for (int r = 0; r < 4; r++)
                    HFp[(((kc2 * 4 + mt) * 64) + quad2 * 16 + quad * 4 + r) * 8 + ii] =
                        (__bf16)fmaxf(acc[mt][r], 0.f);
        }
        __syncthreads();

        {   // GEMM2 + masked column-sum
            const int nt = w & 3, mh = w >> 2;
            f32x4 acc2[2];
            float b2 = bw2[nt * 16 + l16];
#pragma unroll
            for (int m = 0; m < 2; m++) { f32x4 v = {b2, b2, b2, b2}; acc2[m] = v; }
#pragma unroll
            for (int kc = 0; kc < 4; kc++) {
                bf16x8 b2f = Ww2F[(kc * 4 + nt) * 64 + lane];
#pragma unroll
                for (int m = 0; m < 2; m++)
                    acc2[m] = __builtin_amdgcn_mfma_f32_16x16x32_bf16(
                        U.s.HF[(kc * 4 + mh * 2 + m) * 64 + lane], b2f, acc2[m], 0, 0, 0);
            }
            float s = 0.f;
#pragma unroll
            for (int m = 0; m < 2; m++)
#pragma unroll
                for (int r = 0; r < 4; r++) {
                    int node = n0 + (mh * 2 + m) * 16 + quad * 4 + r;
                    s += (node < NN) ? acc2[m][r] : 0.f;
                }
            s += __shfl_xor(s, 16, 64);
            s += __shfl_xor(s, 32, 64);
            if (quad == 0) atomicAdd(m_agg_w + nt * 16 + l16, s);
        }
        return;
    }

    // ================= edge path (R6 + B-frag register dbuf) =================
    const int e0 = blockIdx.x * 64;          // NE % 64 == 0

    {   // ---- gather: 8 threads/edge (side 0 = src, side 1 = tgt) ----
        const int ee = t >> 3, q = t & 7;
        const int side = q >> 2, sub = q & 3;
        const int mt = ee >> 4, l16e = ee & 15;
        const int eg = e0 + ee;
        const int row = side ? ei[NE + eg] : ei[eg];
        if (q == 4) tgt_s[ee] = row;
        const float4* zr = (const float4*)(z_h + (long)row * 64) + sub * 4;
        float4 a0 = zr[0], a1 = zr[1], a2 = zr[2], a3 = zr[3];
        const int kcs = (sub >> 1) + side * 2, qa = (sub & 1) * 2;
        U.XF[(kcs * 4 + mt) * 64 + qa * 16 + l16e]       = pack8(a0, a1);
        U.XF[(kcs * 4 + mt) * 64 + (qa + 1) * 16 + l16e] = pack8(a2, a3);
        if (q == 0) {       // edge features (cols 128..135)
            const float4* zt = (const float4*)(z_h + (long)ei[NE + eg] * 64);
            float4 t0 = zt[0], t1 = zt[1];
            float dx = a0.x - t0.x, dy = a0.y - t0.y, dz = a0.z - t0.z;
            float ax = a0.w, ay = a1.x, az = a1.y;
            float bx = t0.w, by = t1.x, bz = t1.y;
            float cx = ay * bz - az * by;
            float cy = az * bx - ax * bz;
            float cz = ax * by - ay * bx;
            bf16x8 f;
            f[0] = (__bf16)dx; f[1] = (__bf16)dy; f[2] = (__bf16)dz;
            f[3] = (__bf16)(dx * dx + dy * dy + dz * dz);
            f[4] = (__bf16)cx; f[5] = (__bf16)cy; f[6] = (__bf16)cz;
            f[7] = (__bf16)sqrtf(cx * cx + cy * cy + cz * cz);
            U.XF[(16 + mt) * 64 + l16e] = f;
        } else if (q >= 5) { // zero pad (cols 136..159)
            bf16x8 z;
#pragma unroll
            for (int i = 0; i < 8; i++) z[i] = (__bf16)0.f;
            U.XF[(16 + mt) * 64 + (q - 4) * 16 + l16e] = z;
        }
    }
    __syncthreads();                         // B1: XF ready

    // ---- GEMM1: wave owns 32 cols (tiles 2w, 2w+1), 1-ahead B prefetch ----
    f32x4 acc[4][2];
#pragma unroll
    for (int nt = 0; nt < 2; nt++) {
        int col = (w * 2 + nt) * 16 + l16;
        float b = (col < 128) ? be1[col] : bg1[col - 128];
#pragma unroll
        for (int mt = 0; mt < 4; mt++) { f32x4 v = {b, b, b, b}; acc[mt][nt] = v; }
    }
    bf16x8 bcur0 = We1F[(w * 2) * 64 + lane];
    bf16x8 bcur1 = We1F[(w * 2 + 1) * 64 + lane];
#pragma unroll
    for (int kc = 0; kc < 5; kc++) {
        bf16x8 bnx0, bnx1;
        if (kc < 4) {
            bnx0 = We1F[((kc + 1) * 16 + w * 2) * 64 + lane];
            bnx1 = We1F[((kc + 1) * 16 + w * 2 + 1) * 64 + lane];
        }
#pragma unroll
        for (int mt = 0; mt < 4; mt++) {
            bf16x8 af = U.XF[(kc * 4 + mt) * 64 + lane];
            acc[mt][0] = __builtin_amdgcn_mfma_f32_16x16x32_bf16(af, bcur0, acc[mt][0], 0, 0, 0);
            acc[mt][1] = __builtin_amdgcn_mfma_f32_16x16x32_bf16(af, bcur1, acc[mt][1], 0, 0, 0);
        }
        bcur0 = bnx0; bcur1 = bnx1;
    }
    __syncthreads();                         // B2: XF reads done (HF may overwrite)

    if (w < 4) {
        // ---- message waves: relu + transpose into HF (GEMM2-A order) ----
        __bf16* HFp = (__bf16*)U.s.HF;
#pragma unroll
        for (int nt = 0; nt < 2; nt++) {
            int cw = (w * 2 + nt) * 16 + l16;
            int kc2 = cw >> 5, quad2 = (cw >> 3) & 3, ii = cw & 7;
#pragma unroll
            for (int mt = 0; mt < 4; mt++)
#pragma unroll
                for (int r = 0; r < 4; r++)
                    HFp[(((kc2 * 4 + mt) * 64) + quad2 * 16 + quad * 4 + r) * 8 + ii] =
                        (__bf16)fmaxf(acc[mt][nt][r], 0.f);
        }
    } else {
        // ---- gate waves: in-register partials over their 32 gate cols ----
        float gp[4][4];
#pragma unroll
        for (int mt = 0; mt < 4; mt++)
#pragma unroll
            for (int r = 0; r < 4; r++) gp[mt][r] = 0.f;
#pragma unroll
        for (int nt = 0; nt < 2; nt++) {
            float wg = Wg2[((w - 4) * 2 + nt) * 16 + l16];
#pragma unroll
            for (int mt = 0; mt < 4; mt++)
#pragma unroll
                for (int r = 0; r < 4; r++)
                    gp[mt][r] += fmaxf(acc[mt][nt][r], 0.f) * wg;
        }
#pragma unroll
        for (int mask = 1; mask < 16; mask <<= 1)
#pragma unroll
            for (int mt = 0; mt < 4; mt++)
#pragma unroll
                for (int r = 0; r < 4; r++)
                    gp[mt][r] += __shfl_xor(gp[mt][r], mask, 64);
        if (l16 == 0) {
#pragma unroll
            for (int mt = 0; mt < 4; mt++)
#pragma unroll
                for (int r = 0; r < 4; r++)
                    gred[(w - 4) & 3][mt * 16 + quad * 4 + r] = gp[mt][r];
        }
    }
    __syncthreads();                         // B3: HF + gred ready

    if (t < 64) {                            // 64 sigmoids per block
        float g = bg2[0] + gred[0][t] + gred[1][t] + gred[2][t] + gred[3][t];
        wgt[t] = 1.f / (1.f + __expf(-g));
    }

    // ---- GEMM2 (waves 0-3, R0 form): message = H @ We2 + be2 ----
    f32x4 acc2[4];
    if (w < 4) {
        float b2 = be2[w * 16 + l16];
#pragma unroll
        for (int mt = 0; mt < 4; mt++) { f32x4 v = {b2, b2, b2, b2}; acc2[mt] = v; }
        bf16x8 c2 = We2F[w * 64 + lane];
#pragma unroll
        for (int kc = 0; kc < 4; kc++) {
            bf16x8 n2;
            if (kc < 3) n2 = We2F[((kc + 1) * 4 + w) * 64 + lane];
#pragma unroll
            for (int mt = 0; mt < 4; mt++)
                acc2[mt] = __builtin_amdgcn_mfma_f32_16x16x32_bf16(
                    U.s.HF[(kc * 4 + mt) * 64 + lane], c2, acc2[mt], 0, 0, 0);
            c2 = n2;
        }
    }
    __syncthreads();                         // B4: wgt ready, GEMM2 done

    if (w < 4) {
        // ---- weighted messages -> LDS f16 (stride 68: conflict-free) ----
#pragma unroll
        for (int mt = 0; mt < 4; mt++)
#pragma unroll
            for (int r = 0; r < 4; r++) {
                int edge = mt * 16 + quad * 4 + r;
                U.s.M[edge * 68 + w * 16 + l16] =
                    (_Float16)(acc2[mt][r] * wgt[edge]);
            }
    }
    __syncthreads();                         // B5: M ready

    // ---- scatter: all 8 waves, packed v2f16 atomics ----
    // thread t, step k: edge = (t>>5) + 16k, pair p = t&31.
    // per wave-instr: 2 rows x 128 B = 4 cachelines x 16 lanes.
    {
        const int p = t & 31, eb = t >> 5;
        char* base = (char*)magg_rows;
#pragma unroll
        for (int k = 0; k < 4; k++) {
            int e = eb + k * 16;
            f16x2 v = *(const f16x2*)&U.s.M[e * 68 + p * 2];
            pk_atomic_add_f16(base + (long)tgt_s[e] * 256 + p * 4, v);
        }
    }
}

// ---------------- node kernel: 512 thr, N-split, weights once/block ---------
__global__ __launch_bounds__(512, 4) void node_kernel(
    const float* __restrict__ z_h,
    const float* __restrict__ m_agg_w,
    const bf16x8* __restrict__ Wn1F, const bf16x8* __restrict__ Wn2F,
    const float* __restrict__ bn1, const float* __restrict__ bn2,
    float* __restrict__ outp)     // rows double as f16 m_agg accumulator
{
    __shared__ union { bf16x8 XF[1024]; bf16x8 HF[1024]; } U;   // 16 KB
    const int t = threadIdx.x;
    const int n0 = blockIdx.x * 64;
    const int lane = t & 63, w = t >> 6;
    const int quad = lane >> 4, l16 = lane & 15;

    {   // gather: 8 threads/node; halves: z | m_agg(f16 in out row) + m_agg_w
        int nn = t >> 3, q = t & 7;
        int mt = nn >> 4, l16e = nn & 15;
        int node = n0 + nn; if (node >= NN) node = NN - 1;
        int half = q >> 2, sub = q & 3;
        bf16x8 c0, c1;
        if (half == 0) {
            const float4* zr = (const float4*)(z_h + (long)node * 64) + sub * 4;
            c0 = pack8(zr[0], zr[1]);
            c1 = pack8(zr[2], zr[3]);
        } else {
            const f16x8* mr = (const f16x8*)((const char*)outp + (long)node * 256) + sub * 2;
            f16x8 r0 = mr[0], r1 = mr[1];
            const float* mw = m_agg_w + sub * 16;
#pragma unroll
            for (int i = 0; i < 8; i++) {
                c0[i] = (__bf16)((float)r0[i] + mw[i]);
                c1[i] = (__bf16)((float)r1[i] + mw[i + 8]);
            }
        }
        int kcs = (sub >> 1) + half * 2, qa = (sub & 1) * 2;
        U.XF[(kcs * 4 + mt) * 64 + qa * 16 + l16e]       = c0;
        U.XF[(kcs * 4 + mt) * 64 + (qa + 1) * 16 + l16e] = c1;
    }
    __syncthreads();                         // B1 (all m_agg reads done)

    f32x4 acc[4];
    {
        float b = bn1[w * 16 + l16];
#pragma unroll
        for (int mt = 0; mt < 4; mt++) { f32x4 v = {b, b, b, b}; acc[mt] = v; }
    }
#pragma unroll
    for (int kc = 0; kc < 4; kc++) {
        bf16x8 bfr = Wn1F[(kc * 8 + w) * 64 + lane];
#pragma unroll
        for (int mt = 0; mt < 4; mt++)
            acc[mt] = __builtin_amdgcn_mfma_f32_16x16x32_bf16(
                U.XF[(kc * 4 + mt) * 64 + lane], bfr, acc[mt], 0, 0, 0);
    }
    __syncthreads();                         // B2

    {   // relu + transpose -> HF
        __bf16* HFp = (__bf16*)U.HF;
        int cw = w * 16 + l16;
        int kc2 = cw >> 5, quad2 = (cw >> 3) & 3, ii = cw & 7;
#pragma unroll
        for (int mt = 0; mt < 4; mt++)
#pragma unroll
            for (int r = 0; r < 4; r++)
                HFp[(((kc2 * 4 + mt) * 64) + quad2 * 16 + quad * 4 + r) * 8 + ii] =
                    (__bf16)fmaxf(acc[mt][r], 0.f);
    }
    __syncthreads();                         // B3

    {   // GEMM2 + store: nt = w&3, m-half mh = w>>2
        const int nt = w & 3, mh = w >> 2;
        f32x4 acc2[2];
        float b2 = bn2[nt * 16 + l16];
#pragma unroll
        for (int m = 0; m < 2; m++) { f32x4 v = {b2, b2, b2, b2}; acc2[m] = v; }
#pragma unroll
        for (int kc = 0; kc < 4; kc++) {
            bf16x8 b2f = Wn2F[(kc * 4 + nt) * 64 + lane];
#pragma unroll
            for (int m = 0; m < 2; m++)
                acc2[m] = __builtin_amdgcn_mfma_f32_16x16x32_bf16(
                    U.HF[(kc * 4 + mh * 2 + m) * 64 + lane], b2f, acc2[m], 0, 0, 0);
        }
#pragma unroll
        for (int m = 0; m < 2; m++)
#pragma unroll
            for (int r = 0; r < 4; r++) {
                int node = n0 + (mh * 2 + m) * 16 + quad * 4 + r;
                if (node < NN)
                    outp[(long)node * 64 + nt * 16 + l16] = acc2[m][r];
            }
    }
}

extern "C" void kernel_launch(void* const* d_in, const int* in_sizes, int n_in,
                              void* d_out, int out_size, void* d_ws, size_t ws_size,
                              hipStream_t stream)
{
    const float* z_h       = (const float*)d_in[0];
    const float* pos_world = (const float*)d_in[1];
    const int*   ei        = (const int*)d_in[2];
    const float* We1 = (const float*)d_in[3];  const float* be1 = (const float*)d_in[4];
    const float* We2 = (const float*)d_in[5];  const float* be2 = (const float*)d_in[6];
    const float* Wg1 = (const float*)d_in[7];  const float* bg1 = (const float*)d_in[8];
    const float* Wg2 = (const float*)d_in[9];  const float* bg2 = (const float*)d_in[10];
    const float* Wn1 = (const float*)d_in[11]; const float* bn1 = (const float*)d_in[12];
    const float* Wn2 = (const float*)d_in[13]; const float* bn2 = (const float*)d_in[14];
    const float* Ww1 = (const float*)d_in[15]; const float* bw1 = (const float*)d_in[16];
    const float* Ww2 = (const float*)d_in[17]; const float* bw2 = (const float*)d_in[18];

    float*  outp    = (float*)d_out;
    float*  m_agg_w = (float*)d_ws;         // 64 floats
    bf16x8* wsF     = (bf16x8*)((char*)d_ws + 256);

    hipMemsetAsync(d_out, 0, (size_t)NN * 64 * sizeof(float), stream);
    hipMemsetAsync(d_ws, 0, 256, stream);

    pack_weights<<<(NCHUNKS + 255) / 256, 256, 0, stream>>>(
        We1, Wg1, We2, Wn1, Wn2, Ww1, Ww2, wsF);
    fused_kernel<<<EBLOCKS + WBLOCKS, 512, 0, stream>>>(
        z_h, ei, wsF + WE1F_OFF, wsF + WE2F_OFF,
        be1, be2, bg1, Wg2, bg2,
        pos_world, wsF + WW1F_OFF, wsF + WW2F_OFF, bw1, bw2,
        outp, m_agg_w);
    node_kernel<<<(NN + 63) / 64, 512, 0, stream>>>(
        z_h, m_agg_w, wsF + WN1F_OFF, wsF + WN2F_OFF, bn1, bn2, outp);
}